// Round 4
// baseline (4362.488 us; speedup 1.0000x reference)
//
#include <hip/hip_runtime.h>
#include <hip/hip_cooperative_groups.h>
#include <math.h>

#define LAYERS 24
#define DM 128
#define E 256
#define NST 16
#define RK 8
#define BATCH 2
#define SEQ 512
#define ROWS (BATCH*SEQ)
#define CS 4
#define NC (SEQ/CS)          // 128 chunks per batch
#define SROWS (SEQ+3)        // 3 zero halo rows per batch plane
#define SPLANE (BATCH*SROWS*DM)
#define NBLK (BATCH*NC)      // 256 blocks

__device__ __forceinline__ float siluf_(float x) { return x / (1.0f + __expf(-x)); }
__device__ __forceinline__ float softplusf_(float x) {
    return (x > 20.0f) ? x : log1pf(__expf(x));
}

// ---------------------------------------------------------------------------
// Fast device-wide barrier (replaces cg::grid.sync()'s ~45us with ~2-5us).
// Generation-counter scheme; requires all blocks resident (cooperative launch).
// Release/acquire chain: writes -> release add(cnt) -> last arriver acq_rel,
// reset cnt, release add(gen) -> spinners acquire gen -> prior writes visible.
// ---------------------------------------------------------------------------
__device__ __forceinline__ void gbar(unsigned* cnt, unsigned* gen)
{
    __syncthreads();
    if (threadIdx.x == 0) {
        __threadfence();
        const unsigned g = __hip_atomic_load(gen, __ATOMIC_RELAXED,
                                             __HIP_MEMORY_SCOPE_AGENT);
        const unsigned a = __hip_atomic_fetch_add(cnt, 1u, __ATOMIC_ACQ_REL,
                                                  __HIP_MEMORY_SCOPE_AGENT);
        if (a == NBLK - 1) {
            __hip_atomic_store(cnt, 0u, __ATOMIC_RELAXED,
                               __HIP_MEMORY_SCOPE_AGENT);
            __hip_atomic_fetch_add(gen, 1u, __ATOMIC_RELEASE,
                                   __HIP_MEMORY_SCOPE_AGENT);
        } else {
            while (__hip_atomic_load(gen, __ATOMIC_ACQUIRE,
                                     __HIP_MEMORY_SCOPE_AGENT) == g) {
                __builtin_amdgcn_s_sleep(2);
            }
        }
        __threadfence();
    }
    __syncthreads();
}

// ---------------------------------------------------------------------------
// k_chain: ALL 24 layers in one cooperative kernel.
// 256 blocks x 256 threads (1 block/CU). Block = (b, chunk c of 4 rows).
// Per layer: phase A (in_proj w/ 3-row halo + conv + silu + gate + x_proj +
// dt_proj + chunk scan-partials) -> gbar -> phase B (prefix over 128
// chunk summaries, 8192 chains on blocks 0..31) -> gbar -> phase C
// (scan recompute + y + out_proj + LN + lin + relu + residual) -> gbar.
// ---------------------------------------------------------------------------
__global__ __launch_bounds__(256) void k_chain(
    const float* __restrict__ Wi, const float* __restrict__ cw,
    const float* __restrict__ cb, const float* __restrict__ Wx,
    const float* __restrict__ Wdt, const float* __restrict__ bdt,
    const float* __restrict__ Alog, const float* __restrict__ Dp,
    const float* __restrict__ Wo, const float* __restrict__ lng,
    const float* __restrict__ lnb, const float* __restrict__ Wl,
    float* __restrict__ s_hist, float* __restrict__ aprod,
    float* __restrict__ bsum, float* __restrict__ h0g,
    unsigned* __restrict__ bar)
{
    unsigned* bcnt = bar;
    unsigned* bgen = bar + 32;     // separate cachelines
    const int bid = blockIdx.x;
    const int tid = threadIdx.x;
    const int b = bid >> 7;
    const int c = bid & (NC - 1);
    const int t0 = c * CS;
    const int e = tid;

    __shared__ float s_s[CS + 3][DM];
    __shared__ float xc_l[CS][E];
    __shared__ float prj[CS][RK + 2 * NST];
    __shared__ float yl[CS][E];
    __shared__ float ml[CS][DM];

    for (int l = 0; l < LAYERS; ++l) {
        const float* __restrict__ sPl = s_hist + (size_t)l * SPLANE;
        {
            const float4* sPc = (const float4*)(sPl + ((size_t)b * SROWS + t0) * DM);
            if (tid < (CS + 3) * DM / 4) ((float4*)s_s)[tid] = sPc[tid];
        }
        __syncthreads();

        // ---- in_proj: thread e -> x-channel e (7 rows incl halo) + z-channel e ----
        float accx[CS + 3], accz[CS];
        #pragma unroll
        for (int r = 0; r < CS + 3; ++r) accx[r] = 0.f;
        #pragma unroll
        for (int r = 0; r < CS; ++r) accz[r] = 0.f;
        {
            const float4* __restrict__ wx4 = (const float4*)(Wi + ((size_t)l * 2 * E + e) * DM);
            const float4* __restrict__ wz4 = (const float4*)(Wi + ((size_t)l * 2 * E + E + e) * DM);
            #pragma unroll 4
            for (int k4 = 0; k4 < DM / 4; ++k4) {
                const float4 wa = wx4[k4];
                const float4 wb = wz4[k4];
                #pragma unroll
                for (int r = 0; r < CS + 3; ++r) {
                    const float4 sv = *(const float4*)&s_s[r][k4 * 4];
                    accx[r] = fmaf(wa.x, sv.x, fmaf(wa.y, sv.y,
                              fmaf(wa.z, sv.z, fmaf(wa.w, sv.w, accx[r]))));
                    if (r >= 3) {
                        float t = accz[r - 3];
                        t = fmaf(wb.x, sv.x, fmaf(wb.y, sv.y,
                            fmaf(wb.z, sv.z, fmaf(wb.w, sv.w, t))));
                        accz[r - 3] = t;
                    }
                }
            }
        }
        // ---- conv + silu, z-gate silu ----
        float xc[CS], zg[CS];
        {
            const float4 w4 = *(const float4*)(cw + ((size_t)l * E + e) * 4);
            const float cbv = cb[(size_t)l * E + e];
            #pragma unroll
            for (int r = 0; r < CS; ++r) {
                float v = cbv;
                v = fmaf(w4.x, accx[r], v);
                v = fmaf(w4.y, accx[r + 1], v);
                v = fmaf(w4.z, accx[r + 2], v);
                v = fmaf(w4.w, accx[r + 3], v);
                v = siluf_(v);
                xc[r] = v;
                xc_l[r][e] = v;
                zg[r] = siluf_(accz[r]);
            }
        }
        __syncthreads();
        // ---- x_proj: 4 rows x 40 outs, K=256 ----
        {
            const int row = tid >> 6, p = tid & 63;
            if (p < RK + 2 * NST) {
                const float4* __restrict__ wp = (const float4*)(Wx + ((size_t)l * 40 + p) * E);
                const float4* __restrict__ xr = (const float4*)xc_l[row];
                float a0 = 0.f, a1 = 0.f, a2 = 0.f, a3 = 0.f;
                #pragma unroll 8
                for (int q4 = 0; q4 < E / 4; ++q4) {
                    const float4 w = wp[q4];
                    const float4 x = xr[q4];
                    a0 = fmaf(w.x, x.x, a0); a1 = fmaf(w.y, x.y, a1);
                    a2 = fmaf(w.z, x.z, a2); a3 = fmaf(w.w, x.w, a3);
                }
                prj[row][p] = (a0 + a1) + (a2 + a3);
            }
        }
        __syncthreads();
        // ---- dt_proj + softplus ----
        float dt[CS];
        {
            const float4 wd0 = *(const float4*)(Wdt + ((size_t)l * E + e) * RK);
            const float4 wd1 = *(const float4*)(Wdt + ((size_t)l * E + e) * RK + 4);
            const float bv = bdt[(size_t)l * E + e];
            #pragma unroll
            for (int r = 0; r < CS; ++r) {
                float s = bv;
                s = fmaf(wd0.x, prj[r][0], s); s = fmaf(wd0.y, prj[r][1], s);
                s = fmaf(wd0.z, prj[r][2], s); s = fmaf(wd0.w, prj[r][3], s);
                s = fmaf(wd1.x, prj[r][4], s); s = fmaf(wd1.y, prj[r][5], s);
                s = fmaf(wd1.z, prj[r][6], s); s = fmaf(wd1.w, prj[r][7], s);
                dt[r] = softplusf_(s);
            }
        }
        // ---- A values ----
        float Av[NST];
        {
            const float4* al4 = (const float4*)(Alog + ((size_t)l * E + e) * NST);
            #pragma unroll
            for (int q = 0; q < 4; ++q) {
                const float4 v = al4[q];
                Av[q * 4 + 0] = -__expf(v.x); Av[q * 4 + 1] = -__expf(v.y);
                Av[q * 4 + 2] = -__expf(v.z); Av[q * 4 + 3] = -__expf(v.w);
            }
        }
        // ---- chunk-local scan partials ----
        {
            float ap[NST], bs[NST];
            #pragma unroll
            for (int n = 0; n < NST; ++n) { ap[n] = 1.f; bs[n] = 0.f; }
            #pragma unroll
            for (int r = 0; r < CS; ++r) {
                const float dtx = dt[r] * xc[r];
                #pragma unroll
                for (int n = 0; n < NST; ++n) {
                    const float dA = __expf(dt[r] * Av[n]);
                    ap[n] *= dA;
                    bs[n] = fmaf(dA, bs[n], dtx * prj[r][RK + n]);
                }
            }
            const size_t base = ((size_t)bid * E + e) * NST;
            #pragma unroll
            for (int q = 0; q < 4; ++q) {
                *(float4*)(aprod + base + q * 4) =
                    make_float4(ap[q*4], ap[q*4+1], ap[q*4+2], ap[q*4+3]);
                *(float4*)(bsum + base + q * 4) =
                    make_float4(bs[q*4], bs[q*4+1], bs[q*4+2], bs[q*4+3]);
            }
        }
        gbar(bcnt, bgen);
        // ---- phase B: prefix over 128 chunk summaries (8192 chains) ----
        if (bid < BATCH * E * NST / 256) {
            const int gi = bid * 256 + tid;
            const int bb = gi >> 12;
            const int en = gi & (E * NST - 1);
            float h = 0.f;
            #pragma unroll 8
            for (int cc = 0; cc < NC; ++cc) {
                const size_t idx = (size_t)(bb * NC + cc) * (E * NST) + en;
                h0g[idx] = h;
                h = fmaf(aprod[idx], h, bsum[idx]);
            }
        }
        gbar(bcnt, bgen);
        // ---- phase C: scan recompute + y ----
        {
            float h[NST];
            const float4* h4 = (const float4*)(h0g + ((size_t)bid * E + e) * NST);
            #pragma unroll
            for (int q = 0; q < 4; ++q) {
                const float4 v = h4[q];
                h[q*4+0] = v.x; h[q*4+1] = v.y; h[q*4+2] = v.z; h[q*4+3] = v.w;
            }
            const float Dv = Dp[(size_t)l * E + e];
            #pragma unroll
            for (int r = 0; r < CS; ++r) {
                const float dtx = dt[r] * xc[r];
                float y = 0.f;
                #pragma unroll
                for (int n = 0; n < NST; ++n) {
                    const float dA = __expf(dt[r] * Av[n]);
                    h[n] = fmaf(dA, h[n], dtx * prj[r][RK + n]);
                    y = fmaf(h[n], prj[r][RK + NST + n], y);
                }
                yl[r][e] = fmaf(xc[r], Dv, y) * zg[r];
            }
        }
        __syncthreads();
        // ---- out_proj + LayerNorm (wave = one row; thread -> d0, d0+64) ----
        const int row = tid >> 6, d0 = tid & 63;
        {
            const float* Wol = Wo + (size_t)l * DM * E;
            const float4* __restrict__ w0 = (const float4*)(Wol + (size_t)d0 * E);
            const float4* __restrict__ w1 = (const float4*)(Wol + (size_t)(d0 + 64) * E);
            const float4* __restrict__ yr = (const float4*)yl[row];
            float a0=0.f,a1=0.f,a2=0.f,a3=0.f,b0=0.f,b1=0.f,b2=0.f,b3=0.f;
            #pragma unroll 8
            for (int q4 = 0; q4 < E / 4; ++q4) {
                const float4 yv = yr[q4];
                const float4 wv0 = w0[q4], wv1 = w1[q4];
                a0 = fmaf(wv0.x, yv.x, a0); a1 = fmaf(wv0.y, yv.y, a1);
                a2 = fmaf(wv0.z, yv.z, a2); a3 = fmaf(wv0.w, yv.w, a3);
                b0 = fmaf(wv1.x, yv.x, b0); b1 = fmaf(wv1.y, yv.y, b1);
                b2 = fmaf(wv1.z, yv.z, b2); b3 = fmaf(wv1.w, yv.w, b3);
            }
            const float mv0 = (a0 + a1) + (a2 + a3);
            const float mv1 = (b0 + b1) + (b2 + b3);
            float s1 = mv0 + mv1;
            float s2 = mv0 * mv0 + mv1 * mv1;
            #pragma unroll
            for (int off = 32; off >= 1; off >>= 1) {
                s1 += __shfl_xor(s1, off);
                s2 += __shfl_xor(s2, off);
            }
            const float mean = s1 * (1.0f / 128.0f);
            const float var = s2 * (1.0f / 128.0f) - mean * mean;
            const float rstd = rsqrtf(var + 1e-5f);
            ml[row][d0]      = fmaf((mv0 - mean) * rstd, lng[(size_t)l * DM + d0],
                                    lnb[(size_t)l * DM + d0]);
            ml[row][d0 + 64] = fmaf((mv1 - mean) * rstd, lng[(size_t)l * DM + d0 + 64],
                                    lnb[(size_t)l * DM + d0 + 64]);
        }
        __syncthreads();
        // ---- lin + relu + residual ----
        {
            const float* Wll = Wl + (size_t)l * DM * DM;
            const float4* __restrict__ w0 = (const float4*)(Wll + (size_t)d0 * DM);
            const float4* __restrict__ w1 = (const float4*)(Wll + (size_t)(d0 + 64) * DM);
            const float4* __restrict__ mr = (const float4*)ml[row];
            float a0=0.f,a1=0.f,a2=0.f,a3=0.f,b0=0.f,b1=0.f,b2=0.f,b3=0.f;
            #pragma unroll 8
            for (int q4 = 0; q4 < DM / 4; ++q4) {
                const float4 xv = mr[q4];
                const float4 wv0 = w0[q4], wv1 = w1[q4];
                a0 = fmaf(wv0.x, xv.x, a0); a1 = fmaf(wv0.y, xv.y, a1);
                a2 = fmaf(wv0.z, xv.z, a2); a3 = fmaf(wv0.w, xv.w, a3);
                b0 = fmaf(wv1.x, xv.x, b0); b1 = fmaf(wv1.y, xv.y, b1);
                b2 = fmaf(wv1.z, xv.z, b2); b3 = fmaf(wv1.w, xv.w, b3);
            }
            const float v0 = fmaxf((a0 + a1) + (a2 + a3), 0.0f);
            const float v1 = fmaxf((b0 + b1) + (b2 + b3), 0.0f);
            float* __restrict__ sN = s_hist + (size_t)(l + 1) * SPLANE;
            const size_t ro = ((size_t)b * SROWS + 3 + t0 + row) * DM;
            sN[ro + d0]      = s_s[3 + row][d0] + v0;
            sN[ro + d0 + 64] = s_s[3 + row][d0 + 64] + v1;
        }
        gbar(bcnt, bgen);
    }
}

// ---------------------------------------------------------------------------
// k_z: z[b,i,j,f] = sum_{l=1..24} s_l[b,i,f]*s_l[b,j,f].
// Tile 16i x 16j x 128f, LDS-staged (16KB/layer). grid = 2*32*32 = 2048.
// ---------------------------------------------------------------------------
__global__ __launch_bounds__(256) void k_z(const float* __restrict__ s_hist,
                                           float* __restrict__ z)
{
    const int bid = blockIdx.x;
    const int jt = bid & 31;
    const int it = (bid >> 5) & 31;
    const int b  = bid >> 10;
    const int tid = threadIdx.x;
    const int q = tid & 31;
    const int u = tid >> 5;
    const int ig = u >> 2;
    const int jg = u & 3;
    const int i0 = it * 16, j0 = jt * 16;

    __shared__ float4 si[16][32];
    __shared__ float4 sj[16][32];

    float4 acc[8][4];
    #pragma unroll
    for (int ii = 0; ii < 8; ++ii)
        #pragma unroll
        for (int jj = 0; jj < 4; ++jj)
            acc[ii][jj] = make_float4(0.f, 0.f, 0.f, 0.f);

    for (int l = 1; l <= LAYERS; ++l) {
        const float* sp = s_hist + (size_t)l * SPLANE + ((size_t)b * SROWS + 3) * DM;
        __syncthreads();
        #pragma unroll
        for (int k = 0; k < 2; ++k) {
            const int idx = k * 256 + tid;
            const int rr = idx >> 5, c4 = idx & 31;
            si[rr][c4] = *(const float4*)(sp + (size_t)(i0 + rr) * DM + c4 * 4);
            sj[rr][c4] = *(const float4*)(sp + (size_t)(j0 + rr) * DM + c4 * 4);
        }
        __syncthreads();
        float4 bv[4];
        #pragma unroll
        for (int jj = 0; jj < 4; ++jj) bv[jj] = sj[jg * 4 + jj][q];
        #pragma unroll
        for (int ii = 0; ii < 8; ++ii) {
            const float4 av = si[ig * 8 + ii][q];
            #pragma unroll
            for (int jj = 0; jj < 4; ++jj) {
                acc[ii][jj].x = fmaf(av.x, bv[jj].x, acc[ii][jj].x);
                acc[ii][jj].y = fmaf(av.y, bv[jj].y, acc[ii][jj].y);
                acc[ii][jj].z = fmaf(av.z, bv[jj].z, acc[ii][jj].z);
                acc[ii][jj].w = fmaf(av.w, bv[jj].w, acc[ii][jj].w);
            }
        }
    }
    #pragma unroll
    for (int ii = 0; ii < 8; ++ii) {
        const int i = i0 + ig * 8 + ii;
        #pragma unroll
        for (int jj = 0; jj < 4; ++jj) {
            const int j = j0 + jg * 4 + jj;
            *(float4*)(z + (((size_t)b * SEQ + i) * SEQ + j) * DM + q * 4) = acc[ii][jj];
        }
    }
}

// ---------------------------------------------------------------------------
extern "C" void kernel_launch(void* const* d_in, const int* in_sizes, int n_in,
                              void* d_out, int out_size, void* d_ws, size_t ws_size,
                              hipStream_t stream)
{
    const float* in_s = (const float*)d_in[0];
    const float* W_in = (const float*)d_in[2];
    const float* cw   = (const float*)d_in[3];
    const float* cb   = (const float*)d_in[4];
    const float* Wx   = (const float*)d_in[5];
    const float* Wdt  = (const float*)d_in[6];
    const float* bdt  = (const float*)d_in[7];
    const float* Alog = (const float*)d_in[8];
    const float* Dp   = (const float*)d_in[9];
    const float* Wo   = (const float*)d_in[10];
    const float* lng  = (const float*)d_in[11];
    const float* lnb  = (const float*)d_in[12];
    const float* Wl   = (const float*)d_in[13];
    float* out = (float*)d_out;

    float* ws = (float*)d_ws;
    float* s_hist = ws;                                   // 25 * SPLANE
    float* aprod  = s_hist + (size_t)25 * SPLANE;         // 2*128*256*16
    float* bsum   = aprod + (size_t)BATCH * NC * E * NST;
    float* h0g    = bsum + (size_t)BATCH * NC * E * NST;
    unsigned* bar = (unsigned*)(h0g + (size_t)BATCH * NC * E * NST);

    hipMemsetAsync(s_hist, 0, (size_t)25 * SPLANE * sizeof(float), stream);
    hipMemsetAsync(bar, 0, 256, stream);
    for (int b = 0; b < BATCH; ++b)
        hipMemcpyAsync(s_hist + ((size_t)b * SROWS + 3) * DM,
                       in_s + (size_t)b * SEQ * DM,
                       (size_t)SEQ * DM * sizeof(float),
                       hipMemcpyDeviceToDevice, stream);

    void* args[] = {
        (void*)&W_in, (void*)&cw, (void*)&cb, (void*)&Wx,
        (void*)&Wdt, (void*)&bdt, (void*)&Alog, (void*)&Dp,
        (void*)&Wo, (void*)&lng, (void*)&lnb, (void*)&Wl,
        (void*)&s_hist, (void*)&aprod, (void*)&bsum, (void*)&h0g,
        (void*)&bar
    };
    hipLaunchCooperativeKernel(reinterpret_cast<void*>(k_chain),
                               dim3(NBLK), dim3(256), args, 0, stream);

    for (int b = 0; b < BATCH; ++b)
        hipMemcpyAsync(out + (size_t)b * SEQ * DM,
                       s_hist + (size_t)LAYERS * SPLANE + ((size_t)b * SROWS + 3) * DM,
                       (size_t)SEQ * DM * sizeof(float),
                       hipMemcpyDeviceToDevice, stream);
    k_z<<<BATCH * 32 * 32, 256, 0, stream>>>(s_hist, out + (size_t)ROWS * DM);
}

// Round 5
// 3154.267 us; speedup vs baseline: 1.3830x; 1.3830x over previous
//
#include <hip/hip_runtime.h>
#include <hip/hip_cooperative_groups.h>
#include <math.h>

#define LAYERS 24
#define DM 128
#define E 256
#define NST 16
#define RK 8
#define BATCH 2
#define SEQ 512
#define ROWS (BATCH*SEQ)
#define CS 4
#define NC (SEQ/CS)          // 128 chunks per batch
#define SROWS (SEQ+3)        // 3 zero halo rows per batch plane
#define SPLANE (BATCH*SROWS*DM)
#define NBLK (BATCH*NC)      // 256 blocks
#define NPFX (BATCH*E*NST/256)  // 32 prefix blocks

__device__ __forceinline__ float siluf_(float x) { return x / (1.0f + __expf(-x)); }
__device__ __forceinline__ float softplusf_(float x) {
    return (x > 20.0f) ? x : log1pf(__expf(x));
}

// ---------------------------------------------------------------------------
// Coherent (cross-XCD visible) scalar access WITHOUT cache-maintenance fences:
// relaxed agent-scope atomics compile to sc0/sc1 loads/stores that go to the
// coherence point directly. No buffer_inv / buffer_wbl2 is ever emitted, so
// the L2s keep the (read-only) weights warm.
// ---------------------------------------------------------------------------
__device__ __forceinline__ float cload(const float* p) {
    return __hip_atomic_load(p, __ATOMIC_RELAXED, __HIP_MEMORY_SCOPE_AGENT);
}
__device__ __forceinline__ void cstore(float* p, float v) {
    __hip_atomic_store(p, v, __ATOMIC_RELAXED, __HIP_MEMORY_SCOPE_AGENT);
}

// Publish: drain this block's coherent stores, then set flag (thread 0).
__device__ __forceinline__ void arrive(unsigned* flag) {
    asm volatile("s_waitcnt vmcnt(0)" ::: "memory");
    __syncthreads();               // all waves drained before flag store
    if (threadIdx.x == 0)
        __hip_atomic_store(flag, 1u, __ATOMIC_RELAXED, __HIP_MEMORY_SCOPE_AGENT);
}
// Wait for one flag (thread 0 spins; relaxed loads -> no cache invalidates).
__device__ __forceinline__ void waitflag(const unsigned* flag) {
    if (threadIdx.x == 0) {
        while (__hip_atomic_load(flag, __ATOMIC_RELAXED,
                                 __HIP_MEMORY_SCOPE_AGENT) == 0u)
            __builtin_amdgcn_s_sleep(1);
    }
    __syncthreads();
    asm volatile("" ::: "memory");
}
// Wait for n flags, one per thread.
__device__ __forceinline__ void waitflags(const unsigned* flags, int n) {
    if ((int)threadIdx.x < n) {
        const unsigned* f = flags + threadIdx.x;
        while (__hip_atomic_load(f, __ATOMIC_RELAXED,
                                 __HIP_MEMORY_SCOPE_AGENT) == 0u)
            __builtin_amdgcn_s_sleep(1);
    }
    __syncthreads();
    asm volatile("" ::: "memory");
}

// ---------------------------------------------------------------------------
// k_chain: ALL 24 layers, one cooperative kernel, flag-based dataflow sync.
// 256 blocks x 256 threads. Block = (b, chunk c of 4 rows).
// ---------------------------------------------------------------------------
__global__ __launch_bounds__(256) void k_chain(
    const float* __restrict__ Wi, const float* __restrict__ cw,
    const float* __restrict__ cb, const float* __restrict__ Wx,
    const float* __restrict__ Wdt, const float* __restrict__ bdt,
    const float* __restrict__ Alog, const float* __restrict__ Dp,
    const float* __restrict__ Wo, const float* __restrict__ lng,
    const float* __restrict__ lnb, const float* __restrict__ Wl,
    float* __restrict__ s_hist, float* __restrict__ aprod,
    float* __restrict__ bsum, float* __restrict__ h0g,
    unsigned* __restrict__ flagA, unsigned* __restrict__ flagB,
    unsigned* __restrict__ flagC)
{
    const int bid = blockIdx.x;
    const int tid = threadIdx.x;
    const int b = bid >> 7;
    const int c = bid & (NC - 1);
    const int t0 = c * CS;
    const int e = tid;

    __shared__ float s_s[CS + 3][DM];
    __shared__ float xc_l[CS][E];
    __shared__ float prj[CS][RK + 2 * NST];
    __shared__ float yl[CS][E];
    __shared__ float ml[CS][DM];

    for (int l = 0; l < LAYERS; ++l) {
        // wait for left neighbor's layer-(l-1) output (3 halo rows)
        if (l > 0 && c > 0) waitflag(flagC + (size_t)(l - 1) * NBLK + bid - 1);

        // ---- stage s rows [t0-3, t0+4) via coherent scalar loads ----
        {
            const float* sPc = s_hist + (size_t)l * SPLANE
                             + ((size_t)b * SROWS + t0) * DM;
            #pragma unroll
            for (int k = 0; k < 4; ++k) {
                const int idx = tid + k * 256;
                if (idx < (CS + 3) * DM)
                    ((float*)s_s)[idx] = cload(sPc + idx);
            }
        }
        __syncthreads();

        // ---- in_proj: thread e -> x-channel e (7 rows incl halo) + z-channel e ----
        float accx[CS + 3], accz[CS];
        #pragma unroll
        for (int r = 0; r < CS + 3; ++r) accx[r] = 0.f;
        #pragma unroll
        for (int r = 0; r < CS; ++r) accz[r] = 0.f;
        {
            const float4* __restrict__ wx4 = (const float4*)(Wi + ((size_t)l * 2 * E + e) * DM);
            const float4* __restrict__ wz4 = (const float4*)(Wi + ((size_t)l * 2 * E + E + e) * DM);
            #pragma unroll 4
            for (int k4 = 0; k4 < DM / 4; ++k4) {
                const float4 wa = wx4[k4];
                const float4 wb = wz4[k4];
                #pragma unroll
                for (int r = 0; r < CS + 3; ++r) {
                    const float4 sv = *(const float4*)&s_s[r][k4 * 4];
                    accx[r] = fmaf(wa.x, sv.x, fmaf(wa.y, sv.y,
                              fmaf(wa.z, sv.z, fmaf(wa.w, sv.w, accx[r]))));
                    if (r >= 3) {
                        float t = accz[r - 3];
                        t = fmaf(wb.x, sv.x, fmaf(wb.y, sv.y,
                            fmaf(wb.z, sv.z, fmaf(wb.w, sv.w, t))));
                        accz[r - 3] = t;
                    }
                }
            }
        }
        // ---- conv + silu, z-gate silu ----
        float xc[CS], zg[CS];
        {
            const float4 w4 = *(const float4*)(cw + ((size_t)l * E + e) * 4);
            const float cbv = cb[(size_t)l * E + e];
            #pragma unroll
            for (int r = 0; r < CS; ++r) {
                float v = cbv;
                v = fmaf(w4.x, accx[r], v);
                v = fmaf(w4.y, accx[r + 1], v);
                v = fmaf(w4.z, accx[r + 2], v);
                v = fmaf(w4.w, accx[r + 3], v);
                v = siluf_(v);
                xc[r] = v;
                xc_l[r][e] = v;
                zg[r] = siluf_(accz[r]);
            }
        }
        __syncthreads();
        // ---- x_proj: 4 rows x 40 outs, K=256 ----
        {
            const int row = tid >> 6, p = tid & 63;
            if (p < RK + 2 * NST) {
                const float4* __restrict__ wp = (const float4*)(Wx + ((size_t)l * 40 + p) * E);
                const float4* __restrict__ xr = (const float4*)xc_l[row];
                float a0 = 0.f, a1 = 0.f, a2 = 0.f, a3 = 0.f;
                #pragma unroll 8
                for (int q4 = 0; q4 < E / 4; ++q4) {
                    const float4 w = wp[q4];
                    const float4 x = xr[q4];
                    a0 = fmaf(w.x, x.x, a0); a1 = fmaf(w.y, x.y, a1);
                    a2 = fmaf(w.z, x.z, a2); a3 = fmaf(w.w, x.w, a3);
                }
                prj[row][p] = (a0 + a1) + (a2 + a3);
            }
        }
        __syncthreads();
        // ---- dt_proj + softplus ----
        float dt[CS];
        {
            const float4 wd0 = *(const float4*)(Wdt + ((size_t)l * E + e) * RK);
            const float4 wd1 = *(const float4*)(Wdt + ((size_t)l * E + e) * RK + 4);
            const float bv = bdt[(size_t)l * E + e];
            #pragma unroll
            for (int r = 0; r < CS; ++r) {
                float s = bv;
                s = fmaf(wd0.x, prj[r][0], s); s = fmaf(wd0.y, prj[r][1], s);
                s = fmaf(wd0.z, prj[r][2], s); s = fmaf(wd0.w, prj[r][3], s);
                s = fmaf(wd1.x, prj[r][4], s); s = fmaf(wd1.y, prj[r][5], s);
                s = fmaf(wd1.z, prj[r][6], s); s = fmaf(wd1.w, prj[r][7], s);
                dt[r] = softplusf_(s);
            }
        }
        // ---- A values ----
        float Av[NST];
        {
            const float4* al4 = (const float4*)(Alog + ((size_t)l * E + e) * NST);
            #pragma unroll
            for (int q = 0; q < 4; ++q) {
                const float4 v = al4[q];
                Av[q * 4 + 0] = -__expf(v.x); Av[q * 4 + 1] = -__expf(v.y);
                Av[q * 4 + 2] = -__expf(v.z); Av[q * 4 + 3] = -__expf(v.w);
            }
        }
        // ---- chunk-local scan partials -> coherent stores ----
        {
            float ap[NST], bs[NST];
            #pragma unroll
            for (int n = 0; n < NST; ++n) { ap[n] = 1.f; bs[n] = 0.f; }
            #pragma unroll
            for (int r = 0; r < CS; ++r) {
                const float dtx = dt[r] * xc[r];
                #pragma unroll
                for (int n = 0; n < NST; ++n) {
                    const float dA = __expf(dt[r] * Av[n]);
                    ap[n] *= dA;
                    bs[n] = fmaf(dA, bs[n], dtx * prj[r][RK + n]);
                }
            }
            const size_t base = ((size_t)bid * E + e) * NST;
            #pragma unroll
            for (int n = 0; n < NST; ++n) {
                cstore(aprod + base + n, ap[n]);
                cstore(bsum + base + n, bs[n]);
            }
        }
        arrive(flagA + (size_t)l * NBLK + bid);

        // ---- phase B: prefix over 128 chunk summaries (32 blocks) ----
        if (bid < NPFX) {
            // need all 128 chunk partials of this batch
            waitflags(flagA + (size_t)l * NBLK + (bid >> 4) * NC, NC);
            const int gi = bid * 256 + tid;
            const int bb = gi >> 12;
            const int en = gi & (E * NST - 1);
            float h = 0.f;
            #pragma unroll 8
            for (int cc = 0; cc < NC; ++cc) {
                const size_t idx = (size_t)(bb * NC + cc) * (E * NST) + en;
                cstore(h0g + idx, h);
                h = fmaf(cload(aprod + idx), h, cload(bsum + idx));
            }
            arrive(flagB + (size_t)l * NPFX + bid);
        }
        // all blocks: wait for the 16 prefix flags of their batch
        waitflags(flagB + (size_t)l * NPFX + (b << 4), 16);

        // ---- phase C: scan recompute + y ----
        {
            float h[NST];
            const size_t hbase = ((size_t)bid * E + e) * NST;
            #pragma unroll
            for (int n = 0; n < NST; ++n) h[n] = cload(h0g + hbase + n);
            const float Dv = Dp[(size_t)l * E + e];
            #pragma unroll
            for (int r = 0; r < CS; ++r) {
                const float dtx = dt[r] * xc[r];
                float y = 0.f;
                #pragma unroll
                for (int n = 0; n < NST; ++n) {
                    const float dA = __expf(dt[r] * Av[n]);
                    h[n] = fmaf(dA, h[n], dtx * prj[r][RK + n]);
                    y = fmaf(h[n], prj[r][RK + NST + n], y);
                }
                yl[r][e] = fmaf(xc[r], Dv, y) * zg[r];
            }
        }
        __syncthreads();
        // ---- out_proj + LayerNorm (wave = one row; thread -> d0, d0+64) ----
        const int row = tid >> 6, d0 = tid & 63;
        {
            const float* Wol = Wo + (size_t)l * DM * E;
            const float4* __restrict__ w0 = (const float4*)(Wol + (size_t)d0 * E);
            const float4* __restrict__ w1 = (const float4*)(Wol + (size_t)(d0 + 64) * E);
            const float4* __restrict__ yr = (const float4*)yl[row];
            float a0=0.f,a1=0.f,a2=0.f,a3=0.f,b0=0.f,b1=0.f,b2=0.f,b3=0.f;
            #pragma unroll 8
            for (int q4 = 0; q4 < E / 4; ++q4) {
                const float4 yv = yr[q4];
                const float4 wv0 = w0[q4], wv1 = w1[q4];
                a0 = fmaf(wv0.x, yv.x, a0); a1 = fmaf(wv0.y, yv.y, a1);
                a2 = fmaf(wv0.z, yv.z, a2); a3 = fmaf(wv0.w, yv.w, a3);
                b0 = fmaf(wv1.x, yv.x, b0); b1 = fmaf(wv1.y, yv.y, b1);
                b2 = fmaf(wv1.z, yv.z, b2); b3 = fmaf(wv1.w, yv.w, b3);
            }
            const float mv0 = (a0 + a1) + (a2 + a3);
            const float mv1 = (b0 + b1) + (b2 + b3);
            float s1 = mv0 + mv1;
            float s2 = mv0 * mv0 + mv1 * mv1;
            #pragma unroll
            for (int off = 32; off >= 1; off >>= 1) {
                s1 += __shfl_xor(s1, off);
                s2 += __shfl_xor(s2, off);
            }
            const float mean = s1 * (1.0f / 128.0f);
            const float var = s2 * (1.0f / 128.0f) - mean * mean;
            const float rstd = rsqrtf(var + 1e-5f);
            ml[row][d0]      = fmaf((mv0 - mean) * rstd, lng[(size_t)l * DM + d0],
                                    lnb[(size_t)l * DM + d0]);
            ml[row][d0 + 64] = fmaf((mv1 - mean) * rstd, lng[(size_t)l * DM + d0 + 64],
                                    lnb[(size_t)l * DM + d0 + 64]);
        }
        __syncthreads();
        // ---- lin + relu + residual -> coherent stores to plane l+1 ----
        {
            const float* Wll = Wl + (size_t)l * DM * DM;
            const float4* __restrict__ w0 = (const float4*)(Wll + (size_t)d0 * DM);
            const float4* __restrict__ w1 = (const float4*)(Wll + (size_t)(d0 + 64) * DM);
            const float4* __restrict__ mr = (const float4*)ml[row];
            float a0=0.f,a1=0.f,a2=0.f,a3=0.f,b0=0.f,b1=0.f,b2=0.f,b3=0.f;
            #pragma unroll 8
            for (int q4 = 0; q4 < DM / 4; ++q4) {
                const float4 xv = mr[q4];
                const float4 wv0 = w0[q4], wv1 = w1[q4];
                a0 = fmaf(wv0.x, xv.x, a0); a1 = fmaf(wv0.y, xv.y, a1);
                a2 = fmaf(wv0.z, xv.z, a2); a3 = fmaf(wv0.w, xv.w, a3);
                b0 = fmaf(wv1.x, xv.x, b0); b1 = fmaf(wv1.y, xv.y, b1);
                b2 = fmaf(wv1.z, xv.z, b2); b3 = fmaf(wv1.w, xv.w, b3);
            }
            const float v0 = fmaxf((a0 + a1) + (a2 + a3), 0.0f);
            const float v1 = fmaxf((b0 + b1) + (b2 + b3), 0.0f);
            float* __restrict__ sN = s_hist + (size_t)(l + 1) * SPLANE;
            const size_t ro = ((size_t)b * SROWS + 3 + t0 + row) * DM;
            cstore(sN + ro + d0,      s_s[3 + row][d0] + v0);
            cstore(sN + ro + d0 + 64, s_s[3 + row][d0 + 64] + v1);
        }
        arrive(flagC + (size_t)l * NBLK + bid);
    }
}

// ---------------------------------------------------------------------------
// k_z: z[b,i,j,f] = sum_{l=1..24} s_l[b,i,f]*s_l[b,j,f].
// Tile 16i x 16j x 128f, LDS-staged. grid = 2*32*32 = 2048.
// ---------------------------------------------------------------------------
__global__ __launch_bounds__(256) void k_z(const float* __restrict__ s_hist,
                                           float* __restrict__ z)
{
    const int bid = blockIdx.x;
    const int jt = bid & 31;
    const int it = (bid >> 5) & 31;
    const int b  = bid >> 10;
    const int tid = threadIdx.x;
    const int q = tid & 31;
    const int u = tid >> 5;
    const int ig = u >> 2;
    const int jg = u & 3;
    const int i0 = it * 16, j0 = jt * 16;

    __shared__ float4 si[16][32];
    __shared__ float4 sj[16][32];

    float4 acc[8][4];
    #pragma unroll
    for (int ii = 0; ii < 8; ++ii)
        #pragma unroll
        for (int jj = 0; jj < 4; ++jj)
            acc[ii][jj] = make_float4(0.f, 0.f, 0.f, 0.f);

    for (int l = 1; l <= LAYERS; ++l) {
        const float* sp = s_hist + (size_t)l * SPLANE + ((size_t)b * SROWS + 3) * DM;
        __syncthreads();
        #pragma unroll
        for (int k = 0; k < 2; ++k) {
            const int idx = k * 256 + tid;
            const int rr = idx >> 5, c4 = idx & 31;
            si[rr][c4] = *(const float4*)(sp + (size_t)(i0 + rr) * DM + c4 * 4);
            sj[rr][c4] = *(const float4*)(sp + (size_t)(j0 + rr) * DM + c4 * 4);
        }
        __syncthreads();
        float4 bv[4];
        #pragma unroll
        for (int jj = 0; jj < 4; ++jj) bv[jj] = sj[jg * 4 + jj][q];
        #pragma unroll
        for (int ii = 0; ii < 8; ++ii) {
            const float4 av = si[ig * 8 + ii][q];
            #pragma unroll
            for (int jj = 0; jj < 4; ++jj) {
                acc[ii][jj].x = fmaf(av.x, bv[jj].x, acc[ii][jj].x);
                acc[ii][jj].y = fmaf(av.y, bv[jj].y, acc[ii][jj].y);
                acc[ii][jj].z = fmaf(av.z, bv[jj].z, acc[ii][jj].z);
                acc[ii][jj].w = fmaf(av.w, bv[jj].w, acc[ii][jj].w);
            }
        }
    }
    #pragma unroll
    for (int ii = 0; ii < 8; ++ii) {
        const int i = i0 + ig * 8 + ii;
        #pragma unroll
        for (int jj = 0; jj < 4; ++jj) {
            const int j = j0 + jg * 4 + jj;
            *(float4*)(z + (((size_t)b * SEQ + i) * SEQ + j) * DM + q * 4) = acc[ii][jj];
        }
    }
}

// ---------------------------------------------------------------------------
extern "C" void kernel_launch(void* const* d_in, const int* in_sizes, int n_in,
                              void* d_out, int out_size, void* d_ws, size_t ws_size,
                              hipStream_t stream)
{
    const float* in_s = (const float*)d_in[0];
    const float* W_in = (const float*)d_in[2];
    const float* cw   = (const float*)d_in[3];
    const float* cb   = (const float*)d_in[4];
    const float* Wx   = (const float*)d_in[5];
    const float* Wdt  = (const float*)d_in[6];
    const float* bdt  = (const float*)d_in[7];
    const float* Alog = (const float*)d_in[8];
    const float* Dp   = (const float*)d_in[9];
    const float* Wo   = (const float*)d_in[10];
    const float* lng  = (const float*)d_in[11];
    const float* lnb  = (const float*)d_in[12];
    const float* Wl   = (const float*)d_in[13];
    float* out = (float*)d_out;

    float* ws = (float*)d_ws;
    float* s_hist = ws;                                   // 25 * SPLANE
    float* aprod  = s_hist + (size_t)25 * SPLANE;         // 2*128*256*16
    float* bsum   = aprod + (size_t)BATCH * NC * E * NST;
    float* h0g    = bsum + (size_t)BATCH * NC * E * NST;
    unsigned* flagA = (unsigned*)(h0g + (size_t)BATCH * NC * E * NST);
    unsigned* flagB = flagA + (size_t)LAYERS * NBLK;
    unsigned* flagC = flagB + (size_t)LAYERS * NPFX;
    const size_t flagBytes = (size_t)LAYERS * (NBLK + NPFX + NBLK) * sizeof(unsigned);

    hipMemsetAsync(s_hist, 0, (size_t)25 * SPLANE * sizeof(float), stream);
    hipMemsetAsync(flagA, 0, flagBytes, stream);
    for (int b = 0; b < BATCH; ++b)
        hipMemcpyAsync(s_hist + ((size_t)b * SROWS + 3) * DM,
                       in_s + (size_t)b * SEQ * DM,
                       (size_t)SEQ * DM * sizeof(float),
                       hipMemcpyDeviceToDevice, stream);

    void* args[] = {
        (void*)&W_in, (void*)&cw, (void*)&cb, (void*)&Wx,
        (void*)&Wdt, (void*)&bdt, (void*)&Alog, (void*)&Dp,
        (void*)&Wo, (void*)&lng, (void*)&lnb, (void*)&Wl,
        (void*)&s_hist, (void*)&aprod, (void*)&bsum, (void*)&h0g,
        (void*)&flagA, (void*)&flagB, (void*)&flagC
    };
    hipLaunchCooperativeKernel(reinterpret_cast<void*>(k_chain),
                               dim3(NBLK), dim3(256), args, 0, stream);

    for (int b = 0; b < BATCH; ++b)
        hipMemcpyAsync(out + (size_t)b * SEQ * DM,
                       s_hist + (size_t)LAYERS * SPLANE + ((size_t)b * SROWS + 3) * DM,
                       (size_t)SEQ * DM * sizeof(float),
                       hipMemcpyDeviceToDevice, stream);
    k_z<<<BATCH * 32 * 32, 256, 0, stream>>>(s_hist, out + (size_t)ROWS * DM);
}

// Round 7
// 2593.261 us; speedup vs baseline: 1.6822x; 1.2163x over previous
//
#include <hip/hip_runtime.h>
#include <math.h>

#define LAYERS 24
#define DM 128
#define E 256
#define NST 16
#define RK 8
#define BATCH 2
#define SEQ 512
#define ROWS (BATCH*SEQ)
#define SP (ROWS*DM)         // one s-plane: 1024*128 floats
#define CS 4
#define NC (SEQ/CS)          // 128 chunks per batch
#define NBLK (BATCH*NC)      // 256 blocks
#define NPFX (BATCH*E*NST/256)  // 32 prefix blocks
#define EN (E*NST)           // 4096 chains per (b,chunk)

__device__ __forceinline__ float siluf_(float x) { return x / (1.0f + __expf(-x)); }
__device__ __forceinline__ float softplusf_(float x) {
    return (x > 20.0f) ? x : log1pf(__expf(x));
}

// ---------------------------------------------------------------------------
// Cross-XCD-visible access without cache-maintenance fences (validated r5):
// relaxed agent-scope atomics -> sc-flagged loads/stores to the coherence
// point; no L2 writeback/invalidate is ever emitted.
// ---------------------------------------------------------------------------
__device__ __forceinline__ float cload(const float* p) {
    return __hip_atomic_load(p, __ATOMIC_RELAXED, __HIP_MEMORY_SCOPE_AGENT);
}
__device__ __forceinline__ void cstore(float* p, float v) {
    __hip_atomic_store(p, v, __ATOMIC_RELAXED, __HIP_MEMORY_SCOPE_AGENT);
}
__device__ __forceinline__ void arrive(unsigned* flag) {
    asm volatile("s_waitcnt vmcnt(0)" ::: "memory");
    __syncthreads();               // all waves drained before flag store
    if (threadIdx.x == 0)
        __hip_atomic_store(flag, 1u, __ATOMIC_RELAXED, __HIP_MEMORY_SCOPE_AGENT);
}
__device__ __forceinline__ void waitflag(const unsigned* flag) {
    if (threadIdx.x == 0) {
        while (__hip_atomic_load(flag, __ATOMIC_RELAXED,
                                 __HIP_MEMORY_SCOPE_AGENT) == 0u)
            __builtin_amdgcn_s_sleep(1);
    }
    __syncthreads();
    asm volatile("" ::: "memory");
}
__device__ __forceinline__ void waitflags(const unsigned* flags, int n) {
    if ((int)threadIdx.x < n) {
        const unsigned* f = flags + threadIdx.x;
        while (__hip_atomic_load(f, __ATOMIC_RELAXED,
                                 __HIP_MEMORY_SCOPE_AGENT) == 0u)
            __builtin_amdgcn_s_sleep(1);
    }
    __syncthreads();
    asm volatile("" ::: "memory");
}

// ---------------------------------------------------------------------------
// k_chain: all 24 layers, flag-based dataflow sync, coalesced coherent data,
// own 4 s-rows persistent in LDS across layers (only 3 halo rows cross blocks).
// 256 blocks x 256 threads; block = (b, chunk c of 4 rows).
// ---------------------------------------------------------------------------
__global__ __launch_bounds__(256) void k_chain(
    const float* __restrict__ in_s,
    const float* __restrict__ Wi, const float* __restrict__ cw,
    const float* __restrict__ cb, const float* __restrict__ Wx,
    const float* __restrict__ Wdt, const float* __restrict__ bdt,
    const float* __restrict__ Alog, const float* __restrict__ Dp,
    const float* __restrict__ Wo, const float* __restrict__ lng,
    const float* __restrict__ lnb, const float* __restrict__ Wl,
    float* __restrict__ s_hist, float* __restrict__ aprod,
    float* __restrict__ bsum, float* __restrict__ h0g,
    unsigned* __restrict__ flagA, unsigned* __restrict__ flagB,
    unsigned* __restrict__ flagC)
{
    const int bid = blockIdx.x;
    const int tid = threadIdx.x;
    const int b = bid >> 7;
    const int c = bid & (NC - 1);
    const int t0 = c * CS;
    const int e = tid;

    __shared__ float s_s[CS + 3][DM];     // rows 0-2 halo, 3-6 own (persistent)
    __shared__ float xc_l[CS][E];
    __shared__ float prj[CS][RK + 2 * NST];
    __shared__ float yl[CS][E];
    __shared__ float ml[CS][DM];

    // init: own rows from input (coalesced), halo zeros for c==0
    for (int k = tid; k < CS * DM; k += 256)
        ((float*)&s_s[3][0])[k] = in_s[((size_t)b * SEQ + t0) * DM + k];
    if (c == 0)
        for (int k = tid; k < 3 * DM; k += 256)    // FIX r6: 384 elems, 256 thr
            ((float*)s_s)[k] = 0.f;

    for (int l = 0; l < LAYERS; ++l) {
        // ---- halo rows (times t0-3..t0-1) from left neighbor ----
        if (c > 0) {
            if (l == 0) {
                for (int k = tid; k < 3 * DM; k += 256)   // FIX r6
                    ((float*)s_s)[k] = in_s[((size_t)b * SEQ + t0 - 3) * DM + k];
            } else {
                waitflag(flagC + (size_t)(l - 1) * NBLK + bid - 1);
                const float* pl = s_hist + (size_t)(l - 1) * SP
                                + ((size_t)b * SEQ + t0 - 3) * DM;
                for (int k = tid; k < 3 * DM; k += 256)   // FIX r6
                    ((float*)s_s)[k] = cload(pl + k);
            }
        }
        __syncthreads();

        // ---- in_proj: thread e -> x-channel e (7 rows incl halo) + z-channel e ----
        float accx[CS + 3], accz[CS];
        #pragma unroll
        for (int r = 0; r < CS + 3; ++r) accx[r] = 0.f;
        #pragma unroll
        for (int r = 0; r < CS; ++r) accz[r] = 0.f;
        {
            const float4* __restrict__ wx4 = (const float4*)(Wi + ((size_t)l * 2 * E + e) * DM);
            const float4* __restrict__ wz4 = (const float4*)(Wi + ((size_t)l * 2 * E + E + e) * DM);
            #pragma unroll 4
            for (int k4 = 0; k4 < DM / 4; ++k4) {
                const float4 wa = wx4[k4];
                const float4 wb = wz4[k4];
                #pragma unroll
                for (int r = 0; r < CS + 3; ++r) {
                    const float4 sv = *(const float4*)&s_s[r][k4 * 4];  // LDS broadcast
                    accx[r] = fmaf(wa.x, sv.x, fmaf(wa.y, sv.y,
                              fmaf(wa.z, sv.z, fmaf(wa.w, sv.w, accx[r]))));
                    if (r >= 3) {
                        float t = accz[r - 3];
                        t = fmaf(wb.x, sv.x, fmaf(wb.y, sv.y,
                            fmaf(wb.z, sv.z, fmaf(wb.w, sv.w, t))));
                        accz[r - 3] = t;
                    }
                }
            }
        }
        // ---- conv + silu, z-gate silu ----
        float xc[CS], zg[CS];
        {
            const float4 w4 = *(const float4*)(cw + ((size_t)l * E + e) * 4);
            const float cbv = cb[(size_t)l * E + e];
            #pragma unroll
            for (int r = 0; r < CS; ++r) {
                float v = cbv;
                v = fmaf(w4.x, accx[r], v);
                v = fmaf(w4.y, accx[r + 1], v);
                v = fmaf(w4.z, accx[r + 2], v);
                v = fmaf(w4.w, accx[r + 3], v);
                v = siluf_(v);
                xc[r] = v;
                xc_l[r][e] = v;
                zg[r] = siluf_(accz[r]);
            }
        }
        __syncthreads();
        // ---- x_proj: 4 rows x 40 outs, K=256 ----
        {
            const int row = tid >> 6, p = tid & 63;
            if (p < RK + 2 * NST) {
                const float4* __restrict__ wp = (const float4*)(Wx + ((size_t)l * 40 + p) * E);
                const float4* __restrict__ xr = (const float4*)xc_l[row];
                float a0 = 0.f, a1 = 0.f, a2 = 0.f, a3 = 0.f;
                #pragma unroll 8
                for (int q4 = 0; q4 < E / 4; ++q4) {
                    const float4 w = wp[q4];
                    const float4 x = xr[q4];
                    a0 = fmaf(w.x, x.x, a0); a1 = fmaf(w.y, x.y, a1);
                    a2 = fmaf(w.z, x.z, a2); a3 = fmaf(w.w, x.w, a3);
                }
                prj[row][p] = (a0 + a1) + (a2 + a3);
            }
        }
        __syncthreads();
        // ---- dt_proj + softplus ----
        float dt[CS];
        {
            const float4 wd0 = *(const float4*)(Wdt + ((size_t)l * E + e) * RK);
            const float4 wd1 = *(const float4*)(Wdt + ((size_t)l * E + e) * RK + 4);
            const float bv = bdt[(size_t)l * E + e];
            #pragma unroll
            for (int r = 0; r < CS; ++r) {
                float s = bv;
                s = fmaf(wd0.x, prj[r][0], s); s = fmaf(wd0.y, prj[r][1], s);
                s = fmaf(wd0.z, prj[r][2], s); s = fmaf(wd0.w, prj[r][3], s);
                s = fmaf(wd1.x, prj[r][4], s); s = fmaf(wd1.y, prj[r][5], s);
                s = fmaf(wd1.z, prj[r][6], s); s = fmaf(wd1.w, prj[r][7], s);
                dt[r] = softplusf_(s);
            }
        }
        // ---- A values ----
        float Av[NST];
        {
            const float4* al4 = (const float4*)(Alog + ((size_t)l * E + e) * NST);
            #pragma unroll
            for (int q = 0; q < 4; ++q) {
                const float4 v = al4[q];
                Av[q * 4 + 0] = -__expf(v.x); Av[q * 4 + 1] = -__expf(v.y);
                Av[q * 4 + 2] = -__expf(v.z); Av[q * 4 + 3] = -__expf(v.w);
            }
        }
        // ---- chunk-local scan partials -> coalesced coherent stores ----
        {
            float ap[NST], bs[NST];
            #pragma unroll
            for (int n = 0; n < NST; ++n) { ap[n] = 1.f; bs[n] = 0.f; }
            #pragma unroll
            for (int r = 0; r < CS; ++r) {
                const float dtx = dt[r] * xc[r];
                #pragma unroll
                for (int n = 0; n < NST; ++n) {
                    const float dA = __expf(dt[r] * Av[n]);
                    ap[n] *= dA;
                    bs[n] = fmaf(dA, bs[n], dtx * prj[r][RK + n]);
                }
            }
            const size_t base = (size_t)bid * EN;        // [bid][n][e] layout
            #pragma unroll
            for (int n = 0; n < NST; ++n) {
                cstore(aprod + base + n * E + e, ap[n]);
                cstore(bsum  + base + n * E + e, bs[n]);
            }
        }
        arrive(flagA + (size_t)l * NBLK + bid);

        // ---- phase B: prefix over 128 chunk summaries (32 blocks) ----
        if (bid < NPFX) {
            waitflags(flagA + (size_t)l * NBLK + (bid >> 4) * NC, NC);
            const int gi = bid * 256 + tid;
            const int bb = gi >> 12;
            const int en = gi & (EN - 1);
            float h = 0.f;
            #pragma unroll 8
            for (int cc = 0; cc < NC; ++cc) {
                const size_t idx = (size_t)(bb * NC + cc) * EN + en;
                cstore(h0g + idx, h);
                h = fmaf(cload(aprod + idx), h, cload(bsum + idx));
            }
            arrive(flagB + (size_t)l * NPFX + bid);
        }
        waitflags(flagB + (size_t)l * NPFX + (b << 4), 16);

        // ---- phase C: scan recompute + y ----
        {
            float h[NST];
            const size_t hb = (size_t)bid * EN;
            #pragma unroll
            for (int n = 0; n < NST; ++n) h[n] = cload(h0g + hb + n * E + e);
            const float Dv = Dp[(size_t)l * E + e];
            #pragma unroll
            for (int r = 0; r < CS; ++r) {
                const float dtx = dt[r] * xc[r];
                float y = 0.f;
                #pragma unroll
                for (int n = 0; n < NST; ++n) {
                    const float dA = __expf(dt[r] * Av[n]);
                    h[n] = fmaf(dA, h[n], dtx * prj[r][RK + n]);
                    y = fmaf(h[n], prj[r][RK + NST + n], y);
                }
                yl[r][e] = fmaf(xc[r], Dv, y) * zg[r];
            }
        }
        __syncthreads();
        // ---- out_proj + LayerNorm (wave = one row; thread -> d0, d0+64) ----
        const int row = tid >> 6, d0 = tid & 63;
        float mv0, mv1;
        {
            const float* Wol = Wo + (size_t)l * DM * E;
            const float4* __restrict__ w0 = (const float4*)(Wol + (size_t)d0 * E);
            const float4* __restrict__ w1 = (const float4*)(Wol + (size_t)(d0 + 64) * E);
            const float4* __restrict__ yr = (const float4*)yl[row];
            float a0=0.f,a1=0.f,a2=0.f,a3=0.f,b0=0.f,b1=0.f,b2=0.f,b3=0.f;
            #pragma unroll 8
            for (int q4 = 0; q4 < E / 4; ++q4) {
                const float4 yv = yr[q4];
                const float4 wv0 = w0[q4], wv1 = w1[q4];
                a0 = fmaf(wv0.x, yv.x, a0); a1 = fmaf(wv0.y, yv.y, a1);
                a2 = fmaf(wv0.z, yv.z, a2); a3 = fmaf(wv0.w, yv.w, a3);
                b0 = fmaf(wv1.x, yv.x, b0); b1 = fmaf(wv1.y, yv.y, b1);
                b2 = fmaf(wv1.z, yv.z, b2); b3 = fmaf(wv1.w, yv.w, b3);
            }
            mv0 = (a0 + a1) + (a2 + a3);
            mv1 = (b0 + b1) + (b2 + b3);
            float s1 = mv0 + mv1;
            float s2 = mv0 * mv0 + mv1 * mv1;
            #pragma unroll
            for (int off = 32; off >= 1; off >>= 1) {
                s1 += __shfl_xor(s1, off);
                s2 += __shfl_xor(s2, off);
            }
            const float mean = s1 * (1.0f / 128.0f);
            const float var = s2 * (1.0f / 128.0f) - mean * mean;
            const float rstd = rsqrtf(var + 1e-5f);
            ml[row][d0]      = fmaf((mv0 - mean) * rstd, lng[(size_t)l * DM + d0],
                                    lnb[(size_t)l * DM + d0]);
            ml[row][d0 + 64] = fmaf((mv1 - mean) * rstd, lng[(size_t)l * DM + d0 + 64],
                                    lnb[(size_t)l * DM + d0 + 64]);
        }
        __syncthreads();
        // ---- lin + relu + residual; persist in LDS + publish plane l ----
        {
            const float* Wll = Wl + (size_t)l * DM * DM;
            const float4* __restrict__ w0 = (const float4*)(Wll + (size_t)d0 * DM);
            const float4* __restrict__ w1 = (const float4*)(Wll + (size_t)(d0 + 64) * DM);
            const float4* __restrict__ mr = (const float4*)ml[row];
            float a0=0.f,a1=0.f,a2=0.f,a3=0.f,b0=0.f,b1=0.f,b2=0.f,b3=0.f;
            #pragma unroll 8
            for (int q4 = 0; q4 < DM / 4; ++q4) {
                const float4 xv = mr[q4];
                const float4 wv0 = w0[q4], wv1 = w1[q4];
                a0 = fmaf(wv0.x, xv.x, a0); a1 = fmaf(wv0.y, xv.y, a1);
                a2 = fmaf(wv0.z, xv.z, a2); a3 = fmaf(wv0.w, xv.w, a3);
                b0 = fmaf(wv1.x, xv.x, b0); b1 = fmaf(wv1.y, xv.y, b1);
                b2 = fmaf(wv1.z, xv.z, b2); b3 = fmaf(wv1.w, xv.w, b3);
            }
            const float nv0 = s_s[3 + row][d0]      + fmaxf((a0 + a1) + (a2 + a3), 0.0f);
            const float nv1 = s_s[3 + row][d0 + 64] + fmaxf((b0 + b1) + (b2 + b3), 0.0f);
            float* __restrict__ pl = s_hist + (size_t)l * SP;
            const size_t ro = ((size_t)b * SEQ + t0 + row) * DM;
            if (row == 0) {            // row 0: only k_z reads it (after kernel end)
                pl[ro + d0] = nv0;
                pl[ro + d0 + 64] = nv1;
            } else {                   // rows 1-3: neighbor halo -> coherent store
                cstore(pl + ro + d0, nv0);
                cstore(pl + ro + d0 + 64, nv1);
            }
            s_s[3 + row][d0] = nv0;        // persist for next layer (same thread slot)
            s_s[3 + row][d0 + 64] = nv1;
        }
        arrive(flagC + (size_t)l * NBLK + bid);
    }
}

// ---------------------------------------------------------------------------
// k_z: z[b,i,j,f] = sum_{l=0..23} plane_l[b,i,f]*plane_l[b,j,f].
// Tile 16i x 16j x 128f, LDS-staged. grid = 2*32*32 = 2048.
// ---------------------------------------------------------------------------
__global__ __launch_bounds__(256) void k_z(const float* __restrict__ s_hist,
                                           float* __restrict__ z)
{
    const int bid = blockIdx.x;
    const int jt = bid & 31;
    const int it = (bid >> 5) & 31;
    const int b  = bid >> 10;
    const int tid = threadIdx.x;
    const int q = tid & 31;
    const int u = tid >> 5;
    const int ig = u >> 2;
    const int jg = u & 3;
    const int i0 = it * 16, j0 = jt * 16;

    __shared__ float4 si[16][32];
    __shared__ float4 sj[16][32];

    float4 acc[8][4];
    #pragma unroll
    for (int ii = 0; ii < 8; ++ii)
        #pragma unroll
        for (int jj = 0; jj < 4; ++jj)
            acc[ii][jj] = make_float4(0.f, 0.f, 0.f, 0.f);

    for (int l = 0; l < LAYERS; ++l) {
        const float* sp = s_hist + (size_t)l * SP + (size_t)b * SEQ * DM;
        __syncthreads();
        #pragma unroll
        for (int k = 0; k < 2; ++k) {
            const int idx = k * 256 + tid;
            const int rr = idx >> 5, c4 = idx & 31;
            si[rr][c4] = *(const float4*)(sp + (size_t)(i0 + rr) * DM + c4 * 4);
            sj[rr][c4] = *(const float4*)(sp + (size_t)(j0 + rr) * DM + c4 * 4);
        }
        __syncthreads();
        float4 bv[4];
        #pragma unroll
        for (int jj = 0; jj < 4; ++jj) bv[jj] = sj[jg * 4 + jj][q];
        #pragma unroll
        for (int ii = 0; ii < 8; ++ii) {
            const float4 av = si[ig * 8 + ii][q];
            #pragma unroll
            for (int jj = 0; jj < 4; ++jj) {
                acc[ii][jj].x = fmaf(av.x, bv[jj].x, acc[ii][jj].x);
                acc[ii][jj].y = fmaf(av.y, bv[jj].y, acc[ii][jj].y);
                acc[ii][jj].z = fmaf(av.z, bv[jj].z, acc[ii][jj].z);
                acc[ii][jj].w = fmaf(av.w, bv[jj].w, acc[ii][jj].w);
            }
        }
    }
    #pragma unroll
    for (int ii = 0; ii < 8; ++ii) {
        const int i = i0 + ig * 8 + ii;
        #pragma unroll
        for (int jj = 0; jj < 4; ++jj) {
            const int j = j0 + jg * 4 + jj;
            *(float4*)(z + (((size_t)b * SEQ + i) * SEQ + j) * DM + q * 4) = acc[ii][jj];
        }
    }
}

// ---------------------------------------------------------------------------
extern "C" void kernel_launch(void* const* d_in, const int* in_sizes, int n_in,
                              void* d_out, int out_size, void* d_ws, size_t ws_size,
                              hipStream_t stream)
{
    const float* in_s = (const float*)d_in[0];
    const float* W_in = (const float*)d_in[2];
    const float* cw   = (const float*)d_in[3];
    const float* cb   = (const float*)d_in[4];
    const float* Wx   = (const float*)d_in[5];
    const float* Wdt  = (const float*)d_in[6];
    const float* bdt  = (const float*)d_in[7];
    const float* Alog = (const float*)d_in[8];
    const float* Dp   = (const float*)d_in[9];
    const float* Wo   = (const float*)d_in[10];
    const float* lng  = (const float*)d_in[11];
    const float* lnb  = (const float*)d_in[12];
    const float* Wl   = (const float*)d_in[13];
    float* out = (float*)d_out;

    float* ws = (float*)d_ws;
    float* s_hist = ws;                                   // 24 * SP
    float* aprod  = s_hist + (size_t)LAYERS * SP;         // NBLK*EN
    float* bsum   = aprod + (size_t)NBLK * EN;
    float* h0g    = bsum + (size_t)NBLK * EN;
    unsigned* flagA = (unsigned*)(h0g + (size_t)NBLK * EN);
    unsigned* flagB = flagA + (size_t)LAYERS * NBLK;
    unsigned* flagC = flagB + (size_t)LAYERS * NPFX;
    const size_t flagBytes = (size_t)LAYERS * (NBLK + NPFX + NBLK) * sizeof(unsigned);

    hipMemsetAsync(flagA, 0, flagBytes, stream);

    void* args[] = {
        (void*)&in_s,
        (void*)&W_in, (void*)&cw, (void*)&cb, (void*)&Wx,
        (void*)&Wdt, (void*)&bdt, (void*)&Alog, (void*)&Dp,
        (void*)&Wo, (void*)&lng, (void*)&lnb, (void*)&Wl,
        (void*)&s_hist, (void*)&aprod, (void*)&bsum, (void*)&h0g,
        (void*)&flagA, (void*)&flagB, (void*)&flagC
    };
    hipLaunchCooperativeKernel(reinterpret_cast<void*>(k_chain),
                               dim3(NBLK), dim3(256), args, 0, stream);

    hipMemcpyAsync(out, s_hist + (size_t)(LAYERS - 1) * SP,
                   (size_t)SP * sizeof(float), hipMemcpyDeviceToDevice, stream);
    k_z<<<BATCH * 32 * 32, 256, 0, stream>>>(s_hist, out + (size_t)ROWS * DM);
}